// Round 9
// baseline (180.166 us; speedup 1.0000x reference)
//
#include <hip/hip_runtime.h>

typedef float  f32x4   __attribute__((ext_vector_type(4)));
typedef float  v2f     __attribute__((ext_vector_type(2)));
typedef short  short8  __attribute__((ext_vector_type(8)));
typedef unsigned short ushort8 __attribute__((ext_vector_type(8)));

constexpr int kB = 8;
constexpr int kS = 512;
constexpr int kH = 768;
constexpr int kJM = 384;   // max rows of Eqc / cols of EkTc per batch (start in [128,384))

// Values scaled by 2*log2(e) so exp2 gives e^{2x}; tanh(x) = 1 - 2/(e^{2x}+1).
// Additive constants (vb, sum(va)) cancel in softmax.
constexpr float kTanhScale = 2.8853900817779268f;

__device__ __forceinline__ float native_exp2(float x) {
    float r; asm("v_exp_f32 %0, %1" : "=v"(r) : "v"(x)); return r;
}

__device__ __forceinline__ unsigned short bf16_rtn(float x) {
    unsigned u = __float_as_uint(x);
    unsigned r = u + 0x7FFFu + ((u >> 16) & 1u);   // round-to-nearest-even
    return (unsigned short)(r >> 16);
}

__device__ __forceinline__ float waveMax(float v) {
#pragma unroll
    for (int off = 32; off > 0; off >>= 1) v = fmaxf(v, __shfl_xor(v, off, 64));
    return v;
}
__device__ __forceinline__ float waveSum(float v) {
#pragma unroll
    for (int off = 32; off > 0; off >>= 1) v += __shfl_xor(v, off, 64);
    return v;
}

// ---------------- K0: X -> RTN bf16 hi + RTN lo residual; Wa/Ua -> RTN bf16 (hi only).
// X: 786432 float4s, Wa/Ua: 147456 each. Total 1081344 = 4224 blocks * 256.
__global__ __launch_bounds__(256) void k0_convert(
    const float* __restrict__ X, const float* __restrict__ Wa, const float* __restrict__ Ua,
    unsigned short* __restrict__ Xhi, unsigned short* __restrict__ Xlo,
    unsigned short* __restrict__ Wahi, unsigned short* __restrict__ Uahi)
{
    const int i4 = blockIdx.x * 256 + threadIdx.x;
    if (i4 < 786432) {
        float4 v = *(const float4*)(X + (size_t)i4 * 4);
        unsigned short h[4], l[4];
#pragma unroll
        for (int c = 0; c < 4; ++c) {
            float x = (&v.x)[c];
            h[c] = bf16_rtn(x);
            float hf = __uint_as_float((unsigned)h[c] << 16);
            l[c] = bf16_rtn(x - hf);
        }
        *(ushort4*)(Xhi + (size_t)i4 * 4) = make_ushort4(h[0], h[1], h[2], h[3]);
        *(ushort4*)(Xlo + (size_t)i4 * 4) = make_ushort4(l[0], l[1], l[2], l[3]);
    } else {
        const float* src; unsigned short* hi; int off;
        if (i4 < 933888) { src = Wa; hi = Wahi; off = i4 - 786432; }
        else             { src = Ua; hi = Uahi; off = i4 - 933888; }
        float4 v = *(const float4*)(src + (size_t)off * 4);
        *(ushort4*)(hi + (size_t)off * 4) =
            make_ushort4(bf16_rtn(v.x), bf16_rtn(v.y), bf16_rtn(v.z), bf16_rtn(v.w));
    }
}

// ---------------- K1 (MFMA): z=0: Eqc[b][jj][n] = exp2((X·Wa^T+b)*s), jj = t-start (rows t>=start)
//                             z=1: EkTc[b][n][s] = exp2((X·Ua^T+b)*s), cols s < start
// BM=128, BN=96, BK=32; 4 waves each a 64x48 quadrant.
// 2-product bf16: (Xhi + Xlo) x W_rtn  (residual X*(W-Wrtn) ~ 2^-9, within threshold).
__global__ __launch_bounds__(256) void k1_mfma(
    const unsigned short* __restrict__ Xhi, const unsigned short* __restrict__ Xlo,
    const unsigned short* __restrict__ W0hi, const unsigned short* __restrict__ W1hi,
    const float* __restrict__ b0, const float* __restrict__ b1,
    const int* __restrict__ mask,
    float* __restrict__ Eqc, float* __restrict__ EkTc)
{
    // LDS: Ahi [128][40]us @0 | Alo @10240 | Bhi [96][40]us @20480  (28160 B)
    // z=1 epilogue aliases as float stage[128][97] (49664 B)
    __shared__ char smem[49664];
    unsigned short* Ahi = (unsigned short*)smem;
    unsigned short* Alo = (unsigned short*)(smem + 10240);
    unsigned short* Bhi = (unsigned short*)(smem + 20480);

    const int z = blockIdx.z;
    const unsigned short* Whi = z ? W1hi : W0hi;
    const float* bias = z ? b1 : b0;

    const int m0 = blockIdx.y * 128;
    const int n0 = blockIdx.x * 96;
    const int t  = threadIdx.x;
    const int bI = m0 >> 9;            // batch (128 | 512: never straddles)
    const int lb = m0 & (kS - 1);      // local row base within batch
    const int start = mask[2 * bI];

    // dead-block early exit (block-uniform, before any barrier)
    if (z == 0) { if (lb + 128 <= start) return; }
    else        { if (lb >= start) return; }

    // staging roles: 2 threads per row, 16 bf16 each
    const int ar = t >> 1, ko = (t & 1) << 4;
    const bool doB = (ar < 96);
    const size_t aoff = (size_t)(m0 + ar) * kH + ko;
    const size_t woff = (size_t)(n0 + ar) * kH + ko;

    // mfma roles
    const int wid = t >> 6, lane = t & 63;
    const int wr = wid >> 1, wc = wid & 1;
    const int lr = lane & 15, lk = (lane >> 4) << 3;

    f32x4 acc[4][3];
#pragma unroll
    for (int mi = 0; mi < 4; ++mi)
#pragma unroll
        for (int ni = 0; ni < 3; ++ni)
#pragma unroll
            for (int r = 0; r < 4; ++r) acc[mi][ni][r] = 0.0f;

    for (int h0 = 0; h0 < kH; h0 += 32) {
        ushort8 ah0 = *(const ushort8*)(Xhi + aoff + h0);
        ushort8 ah1 = *(const ushort8*)(Xhi + aoff + h0 + 8);
        ushort8 al0 = *(const ushort8*)(Xlo + aoff + h0);
        ushort8 al1 = *(const ushort8*)(Xlo + aoff + h0 + 8);
        ushort8 bh0, bh1;
        if (doB) {
            bh0 = *(const ushort8*)(Whi + woff + h0);
            bh1 = *(const ushort8*)(Whi + woff + h0 + 8);
        }
        __syncthreads();
        *(ushort8*)(Ahi + ar * 40 + ko)     = ah0;
        *(ushort8*)(Ahi + ar * 40 + ko + 8) = ah1;
        *(ushort8*)(Alo + ar * 40 + ko)     = al0;
        *(ushort8*)(Alo + ar * 40 + ko + 8) = al1;
        if (doB) {
            *(ushort8*)(Bhi + ar * 40 + ko)     = bh0;
            *(ushort8*)(Bhi + ar * 40 + ko + 8) = bh1;
        }
        __syncthreads();

        short8 ah[4], al_[4], bh[3];
#pragma unroll
        for (int mi = 0; mi < 4; ++mi) {
            const int row = wr * 64 + mi * 16 + lr;
            ah[mi]  = *(const short8*)(Ahi + row * 40 + lk);
            al_[mi] = *(const short8*)(Alo + row * 40 + lk);
        }
#pragma unroll
        for (int ni = 0; ni < 3; ++ni) {
            const int row = wc * 48 + ni * 16 + lr;
            bh[ni] = *(const short8*)(Bhi + row * 40 + lk);
        }
#pragma unroll
        for (int mi = 0; mi < 4; ++mi)
#pragma unroll
            for (int ni = 0; ni < 3; ++ni)
                acc[mi][ni] = __builtin_amdgcn_mfma_f32_16x16x32_bf16(ah[mi], bh[ni], acc[mi][ni], 0, 0, 0);
#pragma unroll
        for (int mi = 0; mi < 4; ++mi)
#pragma unroll
            for (int ni = 0; ni < 3; ++ni)
                acc[mi][ni] = __builtin_amdgcn_mfma_f32_16x16x32_bf16(al_[mi], bh[ni], acc[mi][ni], 0, 0, 0);
    }

    // C/D frag: col = lane&15, row = (lane>>4)*4 + reg
    if (z == 0) {
#pragma unroll
        for (int mi = 0; mi < 4; ++mi)
#pragma unroll
            for (int ni = 0; ni < 3; ++ni) {
                const int ml = lb + wr * 64 + mi * 16 + ((lane >> 4) << 2);
                const int ng = n0 + wc * 48 + ni * 16 + lr;
                const float bn = bias[ng];
#pragma unroll
                for (int r = 0; r < 4; ++r) {
                    const int jj = ml + r - start;
                    if (jj >= 0)
                        Eqc[((size_t)bI * kJM + jj) * kH + ng] =
                            native_exp2((acc[mi][ni][r] + bn) * kTanhScale);
                }
            }
    } else {
        __syncthreads();                       // tile reads done before aliasing LDS
        float* stg = (float*)smem;             // [128][97]
#pragma unroll
        for (int mi = 0; mi < 4; ++mi)
#pragma unroll
            for (int ni = 0; ni < 3; ++ni) {
                const int ml = wr * 64 + mi * 16 + ((lane >> 4) << 2);
                const int nl = wc * 48 + ni * 16 + lr;
                const float bn = bias[n0 + nl];
#pragma unroll
                for (int r = 0; r < 4; ++r)
                    stg[(ml + r) * 97 + nl] = native_exp2((acc[mi][ni][r] + bn) * kTanhScale);
            }
        __syncthreads();
        const int s4 = (t & 31) << 2, hb_ = t >> 5;
        const int sg = lb + s4;
#pragma unroll
        for (int u = 0; u < 12; ++u) {
            const int h = (u << 3) + hb_;
            float o[4] = { stg[(s4 + 0) * 97 + h], stg[(s4 + 1) * 97 + h],
                           stg[(s4 + 2) * 97 + h], stg[(s4 + 3) * 97 + h] };
            float* dst = EkTc + ((size_t)bI * kH + n0 + h) * kJM + sg;   // FIX: n0 restored
            if (sg + 3 < start) {
                *(float4*)dst = make_float4(o[0], o[1], o[2], o[3]);
            } else {
#pragma unroll
                for (int e2 = 0; e2 < 4; ++e2)
                    if (sg + e2 < start) dst[e2] = o[e2];
            }
        }
    }
}

// ---------------- K2: one wave per item; lane = k; 2 j-rows; 384-wide h-chunk.
// Work item derived inline from mask (no worklist kernel).
// score~ = -2 * sum_h va[h] * rcp(Eq[b,j,h]*Ek[b,h,k] + 1)
__global__ __launch_bounds__(256) void k2_scores(
    const float* __restrict__ Eqc, const float* __restrict__ EkTc,
    const float* __restrict__ va, const int* __restrict__ mask,
    float* __restrict__ part0, float* __restrict__ part1)
{
    const int lane = threadIdx.x & 63;
    const int wslot = (blockIdx.x << 2) | (threadIdx.x >> 6);
    const int nslots = gridDim.x << 2;

    int starts[kB], offs[kB + 1];
    offs[0] = 0;
#pragma unroll
    for (int b = 0; b < kB; ++b) {
        int s = __builtin_amdgcn_readfirstlane(mask[2 * b]);
        starts[b] = s;
        offs[b + 1] = offs[b] + ((kS - s + 1) >> 1) * ((s + 63) >> 6) * 2;
    }
    const int ntiles = offs[kB];
    const v2f one2 = {1.0f, 1.0f};

    for (int w = wslot; w < ntiles; w += nslots) {
        int b = 0;
#pragma unroll
        for (int i = 1; i < kB; ++i) b += (w >= offs[i]);
        const int start = starts[b];
        const int jmax = kS - start;
        const int tt = w - offs[b];
        const int c = tt & 1;
        const int p = tt >> 1;
        const int nkw = (start + 63) >> 6;
        const int jt = p / nkw;
        const int kt = p - jt * nkw;
        const int j0 = jt << 1, k0 = kt << 6;
        const int hbase = c * 384;

        const float* eq0 = Eqc + ((size_t)b * kJM + j0) * kH + hbase;
        const float* eq1 = eq0 + kH;     // j0+1 >= jmax reads stale data; result unstored
        const float* ekp = EkTc + ((size_t)b * kH + hbase) * kJM + k0 + lane;
        const float* vap = va + hbase;

        v2f acc0 = {0.0f, 0.0f}, acc1 = {0.0f, 0.0f};
        float eA[8], eB[8];
#pragma unroll
        for (int c2 = 0; c2 < 8; ++c2) eA[c2] = ekp[(size_t)c2 * kJM];
#pragma unroll
        for (int c2 = 0; c2 < 8; ++c2) eB[c2] = ekp[(size_t)(8 + c2) * kJM];

        for (int h0 = 0; h0 < 384; h0 += 16) {
            const bool more = (h0 + 16) < 384;
            float nA[8], nB[8];
            if (more) {
#pragma unroll
                for (int c2 = 0; c2 < 8; ++c2) nA[c2] = ekp[(size_t)(h0 + 16 + c2) * kJM];
            }
#pragma unroll
            for (int c2 = 0; c2 < 8; c2 += 2) {
                v2f eq0p = *(const v2f*)(eq0 + h0 + c2);
                v2f eq1p = *(const v2f*)(eq1 + h0 + c2);
                v2f vap2 = *(const v2f*)(vap + h0 + c2);
                v2f ek2 = {eA[c2], eA[c2 + 1]};
                v2f p0 = __builtin_elementwise_fma(eq0p, ek2, one2);
                v2f p1 = __builtin_elementwise_fma(eq1p, ek2, one2);
                v2f r0 = {__builtin_amdgcn_rcpf(p0.x), __builtin_amdgcn_rcpf(p0.y)};
                v2f r1 = {__builtin_amdgcn_rcpf(p1.x), __builtin_amdgcn_rcpf(p1.y)};
                acc0 = __builtin_elementwise_fma(vap2, r0, acc0);
                acc1 = __builtin_elementwise_fma(vap2, r1, acc1);
            }
            if (more) {
#pragma unroll
                for (int c2 = 0; c2 < 8; ++c2) nB[c2] = ekp[(size_t)(h0 + 24 + c2) * kJM];
            }
#pragma unroll
            for (int c2 = 0; c2 < 8; c2 += 2) {
                v2f eq0p = *(const v2f*)(eq0 + h0 + 8 + c2);
                v2f eq1p = *(const v2f*)(eq1 + h0 + 8 + c2);
                v2f vap2 = *(const v2f*)(vap + h0 + 8 + c2);
                v2f ek2 = {eB[c2], eB[c2 + 1]};
                v2f p0 = __builtin_elementwise_fma(eq0p, ek2, one2);
                v2f p1 = __builtin_elementwise_fma(eq1p, ek2, one2);
                v2f r0 = {__builtin_amdgcn_rcpf(p0.x), __builtin_amdgcn_rcpf(p0.y)};
                v2f r1 = {__builtin_amdgcn_rcpf(p1.x), __builtin_amdgcn_rcpf(p1.y)};
                acc0 = __builtin_elementwise_fma(vap2, r0, acc0);
                acc1 = __builtin_elementwise_fma(vap2, r1, acc1);
            }
            if (more) {
#pragma unroll
                for (int c2 = 0; c2 < 8; ++c2) { eA[c2] = nA[c2]; eB[c2] = nB[c2]; }
            }
        }

        float* srow = (c ? part1 : part0) + ((size_t)b * kS + j0) * kS + k0 + lane;
        if (j0 < jmax)     srow[0]  = -2.0f * (acc0.x + acc0.y);
        if (j0 + 1 < jmax) srow[kS] = -2.0f * (acc1.x + acc1.y);
    }
}

// ---------------- K3: sum partials + row softmax over k < start; exact zeros elsewhere.
__global__ __launch_bounds__(256) void k3_softmax(
    float* __restrict__ attn, const float* __restrict__ part1,
    const int* __restrict__ mask)
{
    const int bx = blockIdx.x;
    const int b = bx >> 9;
    const int j = bx & (kS - 1);
    const int start = mask[2 * b];
    float* row = attn + ((size_t)b * kS + j) * kS;
    const int tid = threadIdx.x;

    if (j >= kS - start) {
        row[tid] = 0.0f;
        row[tid + 256] = 0.0f;
        return;
    }

    const float* p1row = part1 + ((size_t)b * kS + j) * kS;
    float v0 = (tid < start) ? row[tid] + p1row[tid] : -1e30f;
    float v1 = (tid + 256 < start) ? row[tid + 256] + p1row[tid + 256] : -1e30f;

    __shared__ float red[4];
    const int wid = tid >> 6;

    float m = waveMax(fmaxf(v0, v1));
    if ((tid & 63) == 0) red[wid] = m;
    __syncthreads();
    m = fmaxf(fmaxf(red[0], red[1]), fmaxf(red[2], red[3]));
    __syncthreads();

    float e0 = (tid < start) ? __expf(v0 - m) : 0.0f;
    float e1 = (tid + 256 < start) ? __expf(v1 - m) : 0.0f;
    float s = waveSum(e0 + e1);
    if ((tid & 63) == 0) red[wid] = s;
    __syncthreads();
    s = red[0] + red[1] + red[2] + red[3];

    float inv = __builtin_amdgcn_rcpf(s);
    row[tid] = e0 * inv;
    row[tid + 256] = e1 * inv;
}

// ---------------- K4: ctx[b,j,h] = sum_k attn[b,j,k] * outputs[b,k,h], K bounded by start.
__global__ __launch_bounds__(256) void k4_context(
    const float* __restrict__ attn, const float* __restrict__ outs,
    const int* __restrict__ mask, float* __restrict__ ctx)
{
    const int b = blockIdx.z;
    const int start = mask[2 * b];
    const int kmax = (start + 15) & ~15;
    const int m0 = blockIdx.y * 64;
    const int n0 = blockIdx.x * 64;

    __shared__ float As[16][68];
    __shared__ float Bs[16][68];

    const int tid = threadIdx.x;
    const int lrow = tid >> 2;
    const int lk4  = (tid & 3) << 2;
    const int brow = tid >> 4;
    const int bh4  = (tid & 15) << 2;
    const int is = tid >> 4;
    const int js = tid & 15;

    const float* arow = attn + ((size_t)b * kS + m0 + lrow) * kS + lk4;
    const float* bbase = outs + (size_t)b * kS * kH + n0 + bh4;

    float acc[4][4] = {};

    for (int k0 = 0; k0 < kmax; k0 += 16) {
        float4 av = *(const float4*)(arow + k0);
        float4 bv = *(const float4*)(bbase + (size_t)(k0 + brow) * kH);
        __syncthreads();
        As[lk4 + 0][lrow] = av.x;
        As[lk4 + 1][lrow] = av.y;
        As[lk4 + 2][lrow] = av.z;
        As[lk4 + 3][lrow] = av.w;
        *(float4*)&Bs[brow][bh4] = bv;
        __syncthreads();
#pragma unroll
        for (int kk = 0; kk < 16; ++kk) {
            const float* ap = &As[kk][is << 2];
            const float* bp = &Bs[kk][js << 2];
            float aa[4], bb[4];
#pragma unroll
            for (int c = 0; c < 4; ++c) { aa[c] = ap[c]; bb[c] = bp[c]; }
#pragma unroll
            for (int i = 0; i < 4; ++i)
#pragma unroll
                for (int j = 0; j < 4; ++j)
                    acc[i][j] = fmaf(aa[i], bb[j], acc[i][j]);
        }
    }

#pragma unroll
    for (int i = 0; i < 4; ++i) {
        int row = m0 + (is << 2) + i;
        float4 o = {acc[i][0], acc[i][1], acc[i][2], acc[i][3]};
        *(float4*)(ctx + ((size_t)b * kS + row) * kH + n0 + (js << 2)) = o;
    }
}

extern "C" void kernel_launch(void* const* d_in, const int* in_sizes, int n_in,
                              void* d_out, int out_size, void* d_ws, size_t ws_size,
                              hipStream_t stream)
{
    const float* outputs = (const float*)d_in[0];
    const int*   mask    = (const int*)d_in[1];
    const float* Wa_w    = (const float*)d_in[2];
    const float* Wa_b    = (const float*)d_in[3];
    const float* Ua_w    = (const float*)d_in[4];
    const float* Ua_b    = (const float*)d_in[5];
    const float* Va_w    = (const float*)d_in[6];
    // Va_b and sum(va) cancel in softmax.

    float* attn = (float*)d_out;                          // (B,S,S) 8.39 MB
    float* ctx  = attn + (size_t)kB * kS * kS;            // (B,S,H) 12.58 MB

    // Region reuse over the launch timeline (stream-ordered):
    //   ctx:  [K0..K1] Xhi/Xlo bf16 pair  -> [K2..K3] part1 scores -> [K4] contexts
    //   attn: [K0..K1] W bf16 (hi only)   -> [K2..]   part0 scores / attentions
    unsigned short* Xhi  = (unsigned short*)ctx;                    // 6.29 MB
    unsigned short* Xlo  = Xhi + (size_t)kB * kS * kH;              // 6.29 MB
    unsigned short* Wahi = (unsigned short*)attn;                   // 1.18 MB each
    unsigned short* Uahi = Wahi + (size_t)kH * kH;
    float* part1 = ctx;

    // ws: [Eqc 9.44MB][EkTc 9.44MB] = 18.9 MB (proven available in rounds 6-7)
    float* Eqc  = (float*)d_ws;
    float* EkTc = Eqc + (size_t)kB * kJM * kH;

    // K0: RTN bf16 pre-split of X (hi/lo) and RTN bf16 of Wa/Ua
    k0_convert<<<dim3(4224), 256, 0, stream>>>(
        outputs, Wa_w, Ua_w, Xhi, Xlo, Wahi, Uahi);

    // K1 (MFMA, 2-product): Eqc (compacted rows) and EkTc (compacted cols), exp applied
    k1_mfma<<<dim3(kH / 96, (kB * kS) / 128, 2), 256, 0, stream>>>(
        Xhi, Xlo, Wahi, Uahi, Wa_b, Ua_b, mask, Eqc, EkTc);

    // K2: score partials (h-chunks) into attn (c=0) and part1 (c=1); worklist inline
    k2_scores<<<dim3(2048), 256, 0, stream>>>(Eqc, EkTc, Va_w, mask, attn, part1);

    // K3: sum partials + softmax + exact-zero masking (writes every element of attn)
    k3_softmax<<<dim3(kB * kS), 256, 0, stream>>>(attn, part1, mask);

    // K4: contexts (writes every element of ctx, overwriting part1 scratch)
    k4_context<<<dim3(kH / 64, kS / 64, kB), 256, 0, stream>>>(attn, outputs, mask, ctx);
}

// Round 10
// 145.167 us; speedup vs baseline: 1.2411x; 1.2411x over previous
//
#include <hip/hip_runtime.h>

typedef float  f32x4   __attribute__((ext_vector_type(4)));
typedef short  short8  __attribute__((ext_vector_type(8)));
typedef unsigned short ushort8 __attribute__((ext_vector_type(8)));

constexpr int kB = 8;
constexpr int kS = 512;
constexpr int kH = 768;
constexpr int kJM = 384;   // max rows of Eqc / cols of EkTc per batch (start in [128,384))

// Values scaled by 2*log2(e) so exp2 gives e^{2x}; tanh(x) = 1 - 2/(e^{2x}+1).
// Additive constants (vb, sum(va)) cancel in softmax.
constexpr float kTanhScale = 2.8853900817779268f;

__device__ __forceinline__ float native_exp2(float x) {
    float r; asm("v_exp_f32 %0, %1" : "=v"(r) : "v"(x)); return r;
}

__device__ __forceinline__ unsigned short bf16_rtn(float x) {
    unsigned u = __float_as_uint(x);
    unsigned r = u + 0x7FFFu + ((u >> 16) & 1u);   // round-to-nearest-even
    return (unsigned short)(r >> 16);
}

__device__ __forceinline__ float waveMax(float v) {
#pragma unroll
    for (int off = 32; off > 0; off >>= 1) v = fmaxf(v, __shfl_xor(v, off, 64));
    return v;
}
__device__ __forceinline__ float waveSum(float v) {
#pragma unroll
    for (int off = 32; off > 0; off >>= 1) v += __shfl_xor(v, off, 64);
    return v;
}

// ---------------- K0: X -> RTN bf16 hi + RTN lo residual; Wa/Ua -> RTN bf16 (hi only).
__global__ __launch_bounds__(256) void k0_convert(
    const float* __restrict__ X, const float* __restrict__ Wa, const float* __restrict__ Ua,
    unsigned short* __restrict__ Xhi, unsigned short* __restrict__ Xlo,
    unsigned short* __restrict__ Wahi, unsigned short* __restrict__ Uahi)
{
    const int i4 = blockIdx.x * 256 + threadIdx.x;
    if (i4 < 786432) {
        float4 v = *(const float4*)(X + (size_t)i4 * 4);
        unsigned short h[4], l[4];
#pragma unroll
        for (int c = 0; c < 4; ++c) {
            float x = (&v.x)[c];
            h[c] = bf16_rtn(x);
            float hf = __uint_as_float((unsigned)h[c] << 16);
            l[c] = bf16_rtn(x - hf);
        }
        *(ushort4*)(Xhi + (size_t)i4 * 4) = make_ushort4(h[0], h[1], h[2], h[3]);
        *(ushort4*)(Xlo + (size_t)i4 * 4) = make_ushort4(l[0], l[1], l[2], l[3]);
    } else {
        const float* src; unsigned short* hi; int off;
        if (i4 < 933888) { src = Wa; hi = Wahi; off = i4 - 786432; }
        else             { src = Ua; hi = Uahi; off = i4 - 933888; }
        float4 v = *(const float4*)(src + (size_t)off * 4);
        *(ushort4*)(hi + (size_t)off * 4) =
            make_ushort4(bf16_rtn(v.x), bf16_rtn(v.y), bf16_rtn(v.z), bf16_rtn(v.w));
    }
}

// ---------------- K1 (MFMA): z=0: Eqc[b][jj][n] = exp2((X·Wa^T+b)*s), jj = t-start (rows t>=start)
//                             z=1: EkTc[b][n][s] = exp2((X·Ua^T+b)*s), cols s < start
// BM=128, BN=96, BK=32; 4 waves each a 64x48 quadrant.
// 2-product bf16: (Xhi + Xlo) x W_rtn.
__global__ __launch_bounds__(256) void k1_mfma(
    const unsigned short* __restrict__ Xhi, const unsigned short* __restrict__ Xlo,
    const unsigned short* __restrict__ W0hi, const unsigned short* __restrict__ W1hi,
    const float* __restrict__ b0, const float* __restrict__ b1,
    const int* __restrict__ mask,
    float* __restrict__ Eqc, float* __restrict__ EkTc)
{
    __shared__ char smem[49664];
    unsigned short* Ahi = (unsigned short*)smem;
    unsigned short* Alo = (unsigned short*)(smem + 10240);
    unsigned short* Bhi = (unsigned short*)(smem + 20480);

    const int z = blockIdx.z;
    const unsigned short* Whi = z ? W1hi : W0hi;
    const float* bias = z ? b1 : b0;

    const int m0 = blockIdx.y * 128;
    const int n0 = blockIdx.x * 96;
    const int t  = threadIdx.x;
    const int bI = m0 >> 9;
    const int lb = m0 & (kS - 1);
    const int start = mask[2 * bI];

    if (z == 0) { if (lb + 128 <= start) return; }
    else        { if (lb >= start) return; }

    const int ar = t >> 1, ko = (t & 1) << 4;
    const bool doB = (ar < 96);
    const size_t aoff = (size_t)(m0 + ar) * kH + ko;
    const size_t woff = (size_t)(n0 + ar) * kH + ko;

    const int wid = t >> 6, lane = t & 63;
    const int wr = wid >> 1, wc = wid & 1;
    const int lr = lane & 15, lk = (lane >> 4) << 3;

    f32x4 acc[4][3];
#pragma unroll
    for (int mi = 0; mi < 4; ++mi)
#pragma unroll
        for (int ni = 0; ni < 3; ++ni)
#pragma unroll
            for (int r = 0; r < 4; ++r) acc[mi][ni][r] = 0.0f;

    for (int h0 = 0; h0 < kH; h0 += 32) {
        ushort8 ah0 = *(const ushort8*)(Xhi + aoff + h0);
        ushort8 ah1 = *(const ushort8*)(Xhi + aoff + h0 + 8);
        ushort8 al0 = *(const ushort8*)(Xlo + aoff + h0);
        ushort8 al1 = *(const ushort8*)(Xlo + aoff + h0 + 8);
        ushort8 bh0, bh1;
        if (doB) {
            bh0 = *(const ushort8*)(Whi + woff + h0);
            bh1 = *(const ushort8*)(Whi + woff + h0 + 8);
        }
        __syncthreads();
        *(ushort8*)(Ahi + ar * 40 + ko)     = ah0;
        *(ushort8*)(Ahi + ar * 40 + ko + 8) = ah1;
        *(ushort8*)(Alo + ar * 40 + ko)     = al0;
        *(ushort8*)(Alo + ar * 40 + ko + 8) = al1;
        if (doB) {
            *(ushort8*)(Bhi + ar * 40 + ko)     = bh0;
            *(ushort8*)(Bhi + ar * 40 + ko + 8) = bh1;
        }
        __syncthreads();

        short8 ah[4], al_[4], bh[3];
#pragma unroll
        for (int mi = 0; mi < 4; ++mi) {
            const int row = wr * 64 + mi * 16 + lr;
            ah[mi]  = *(const short8*)(Ahi + row * 40 + lk);
            al_[mi] = *(const short8*)(Alo + row * 40 + lk);
        }
#pragma unroll
        for (int ni = 0; ni < 3; ++ni) {
            const int row = wc * 48 + ni * 16 + lr;
            bh[ni] = *(const short8*)(Bhi + row * 40 + lk);
        }
#pragma unroll
        for (int mi = 0; mi < 4; ++mi)
#pragma unroll
            for (int ni = 0; ni < 3; ++ni)
                acc[mi][ni] = __builtin_amdgcn_mfma_f32_16x16x32_bf16(ah[mi], bh[ni], acc[mi][ni], 0, 0, 0);
#pragma unroll
        for (int mi = 0; mi < 4; ++mi)
#pragma unroll
            for (int ni = 0; ni < 3; ++ni)
                acc[mi][ni] = __builtin_amdgcn_mfma_f32_16x16x32_bf16(al_[mi], bh[ni], acc[mi][ni], 0, 0, 0);
    }

    // C/D frag: col = lane&15, row = (lane>>4)*4 + reg
    if (z == 0) {
#pragma unroll
        for (int mi = 0; mi < 4; ++mi)
#pragma unroll
            for (int ni = 0; ni < 3; ++ni) {
                const int ml = lb + wr * 64 + mi * 16 + ((lane >> 4) << 2);
                const int ng = n0 + wc * 48 + ni * 16 + lr;
                const float bn = bias[ng];
#pragma unroll
                for (int r = 0; r < 4; ++r) {
                    const int jj = ml + r - start;
                    if (jj >= 0)
                        Eqc[((size_t)bI * kJM + jj) * kH + ng] =
                            native_exp2((acc[mi][ni][r] + bn) * kTanhScale);
                }
            }
    } else {
        __syncthreads();
        float* stg = (float*)smem;             // [128][97]
#pragma unroll
        for (int mi = 0; mi < 4; ++mi)
#pragma unroll
            for (int ni = 0; ni < 3; ++ni) {
                const int ml = wr * 64 + mi * 16 + ((lane >> 4) << 2);
                const int nl = wc * 48 + ni * 16 + lr;
                const float bn = bias[n0 + nl];
#pragma unroll
                for (int r = 0; r < 4; ++r)
                    stg[(ml + r) * 97 + nl] = native_exp2((acc[mi][ni][r] + bn) * kTanhScale);
            }
        __syncthreads();
        const int s4 = (t & 31) << 2, hb_ = t >> 5;
        const int sg = lb + s4;
#pragma unroll
        for (int u = 0; u < 12; ++u) {
            const int h = (u << 3) + hb_;
            float o[4] = { stg[(s4 + 0) * 97 + h], stg[(s4 + 1) * 97 + h],
                           stg[(s4 + 2) * 97 + h], stg[(s4 + 3) * 97 + h] };
            float* dst = EkTc + ((size_t)bI * kH + n0 + h) * kJM + sg;   // n0 kept!
            if (sg + 3 < start) {
                *(float4*)dst = make_float4(o[0], o[1], o[2], o[3]);
            } else {
#pragma unroll
                for (int e2 = 0; e2 < 4; ++e2)
                    if (sg + e2 < start) dst[e2] = o[e2];
            }
        }
    }
}

// ---------------- K2a: work list of (b, j-tile[4], k-wave[64], h-chunk[2]) items.
__global__ void k2a_worklist(const int* __restrict__ mask, int* __restrict__ wl)
{
    __shared__ int ne[kB], off[kB];
    const int tid = threadIdx.x;
    if (tid < kB) {
        int start = mask[2 * tid];
        ne[tid] = ((kS - start + 3) >> 2) * ((start + 63) >> 6) * 2;
    }
    __syncthreads();
    if (tid == 0) {
        int s = 0;
        for (int b = 0; b < kB; ++b) { off[b] = s; s += ne[b]; }
        wl[0] = s;
    }
    __syncthreads();
    for (int b = 0; b < kB; ++b) {
        int start = mask[2 * b];
        int nkw = (start + 63) >> 6;
        int nkc = nkw * 2;
        int n = ne[b], base = off[b];
        for (int t = tid; t < n; t += blockDim.x) {
            int jt = t / nkc;
            int r = t - jt * nkc;
            int kt = r >> 1, c = r & 1;
            wl[1 + base + t] = (b << 16) | (jt << 8) | (kt << 1) | c;
        }
    }
}

// ---------------- K2: one wave per item; lane = k; 4 j-rows; 384-wide h-chunk.
// score~ = -2 * sum_h va[h] * rcp(Eq[b,j,h]*Ek[b,h,k] + 1)
__global__ __launch_bounds__(256) void k2_scores(
    const float* __restrict__ Eqc, const float* __restrict__ EkTc,
    const float* __restrict__ va, const int* __restrict__ mask,
    const int* __restrict__ wl, float* __restrict__ part0, float* __restrict__ part1)
{
    constexpr int JT = 4;
    const int ntiles = wl[0];
    const int lane = threadIdx.x & 63;
    const int wslot = (blockIdx.x << 2) | (threadIdx.x >> 6);
    const int nslots = gridDim.x << 2;

    for (int w = wslot; w < ntiles; w += nslots) {
        const int e = __builtin_amdgcn_readfirstlane(wl[1 + w]);
        const int b = e >> 16, jt = (e >> 8) & 255, ktc = e & 255;
        const int kt = ktc >> 1, c = ktc & 1;
        const int start = __builtin_amdgcn_readfirstlane(mask[2 * b]);
        const int jmax = kS - start;
        const int j0 = jt * JT, k0 = kt << 6;
        const int hbase = c * 384;

        // rows j0..j0+3 all lie within the kJM=384 allocation (jmax <= 384);
        // rows >= jmax hold stale data, computed but never stored.
        const float* eqr[JT];
#pragma unroll
        for (int j = 0; j < JT; ++j)
            eqr[j] = Eqc + ((size_t)b * kJM + j0 + j) * kH + hbase;
        const float* ekp = EkTc + ((size_t)b * kH + hbase) * kJM + k0 + lane;
        const float* vap = va + hbase;

        float acc[JT] = {};
        float eA[8], eB[8];
#pragma unroll
        for (int c2 = 0; c2 < 8; ++c2) eA[c2] = ekp[(size_t)c2 * kJM];
#pragma unroll
        for (int c2 = 0; c2 < 8; ++c2) eB[c2] = ekp[(size_t)(8 + c2) * kJM];

        for (int h0 = 0; h0 < 384; h0 += 16) {
            const bool more = (h0 + 16) < 384;
            float nA[8], nB[8];
            if (more) {
#pragma unroll
                for (int c2 = 0; c2 < 8; ++c2) nA[c2] = ekp[(size_t)(h0 + 16 + c2) * kJM];
            }
#pragma unroll
            for (int c2 = 0; c2 < 8; ++c2) {
                const float vc = vap[h0 + c2];
#pragma unroll
                for (int j = 0; j < JT; ++j) {
                    float r = __builtin_amdgcn_rcpf(fmaf(eqr[j][h0 + c2], eA[c2], 1.0f));
                    acc[j] = fmaf(vc, r, acc[j]);
                }
            }
            if (more) {
#pragma unroll
                for (int c2 = 0; c2 < 8; ++c2) nB[c2] = ekp[(size_t)(h0 + 24 + c2) * kJM];
            }
#pragma unroll
            for (int c2 = 0; c2 < 8; ++c2) {
                const float vc = vap[h0 + 8 + c2];
#pragma unroll
                for (int j = 0; j < JT; ++j) {
                    float r = __builtin_amdgcn_rcpf(fmaf(eqr[j][h0 + 8 + c2], eB[c2], 1.0f));
                    acc[j] = fmaf(vc, r, acc[j]);
                }
            }
            if (more) {
#pragma unroll
                for (int c2 = 0; c2 < 8; ++c2) { eA[c2] = nA[c2]; eB[c2] = nB[c2]; }
            }
        }

        float* srow = (c ? part1 : part0) + ((size_t)b * kS + j0) * kS + k0 + lane;
#pragma unroll
        for (int j = 0; j < JT; ++j)
            if (j0 + j < jmax) srow[(size_t)j * kS] = -2.0f * acc[j];
    }
}

// ---------------- K3: sum partials + row softmax over k < start; exact zeros elsewhere.
__global__ __launch_bounds__(256) void k3_softmax(
    float* __restrict__ attn, const float* __restrict__ part1,
    const int* __restrict__ mask)
{
    const int bx = blockIdx.x;
    const int b = bx >> 9;
    const int j = bx & (kS - 1);
    const int start = mask[2 * b];
    float* row = attn + ((size_t)b * kS + j) * kS;
    const int tid = threadIdx.x;

    if (j >= kS - start) {
        row[tid] = 0.0f;
        row[tid + 256] = 0.0f;
        return;
    }

    const float* p1row = part1 + ((size_t)b * kS + j) * kS;
    float v0 = (tid < start) ? row[tid] + p1row[tid] : -1e30f;
    float v1 = (tid + 256 < start) ? row[tid + 256] + p1row[tid + 256] : -1e30f;

    __shared__ float red[4];
    const int wid = tid >> 6;

    float m = waveMax(fmaxf(v0, v1));
    if ((tid & 63) == 0) red[wid] = m;
    __syncthreads();
    m = fmaxf(fmaxf(red[0], red[1]), fmaxf(red[2], red[3]));
    __syncthreads();

    float e0 = (tid < start) ? __expf(v0 - m) : 0.0f;
    float e1 = (tid + 256 < start) ? __expf(v1 - m) : 0.0f;
    float s = waveSum(e0 + e1);
    if ((tid & 63) == 0) red[wid] = s;
    __syncthreads();
    s = red[0] + red[1] + red[2] + red[3];

    float inv = __builtin_amdgcn_rcpf(s);
    row[tid] = e0 * inv;
    row[tid + 256] = e1 * inv;
}

// ---------------- K4: ctx[b,j,h] = sum_k attn[b,j,k] * outputs[b,k,h], K bounded by start.
__global__ __launch_bounds__(256) void k4_context(
    const float* __restrict__ attn, const float* __restrict__ outs,
    const int* __restrict__ mask, float* __restrict__ ctx)
{
    const int b = blockIdx.z;
    const int start = mask[2 * b];
    const int kmax = (start + 15) & ~15;
    const int m0 = blockIdx.y * 64;
    const int n0 = blockIdx.x * 64;

    __shared__ float As[16][68];
    __shared__ float Bs[16][68];

    const int tid = threadIdx.x;
    const int lrow = tid >> 2;
    const int lk4  = (tid & 3) << 2;
    const int brow = tid >> 4;
    const int bh4  = (tid & 15) << 2;
    const int is = tid >> 4;
    const int js = tid & 15;

    const float* arow = attn + ((size_t)b * kS + m0 + lrow) * kS + lk4;
    const float* bbase = outs + (size_t)b * kS * kH + n0 + bh4;

    float acc[4][4] = {};

    for (int k0 = 0; k0 < kmax; k0 += 16) {
        float4 av = *(const float4*)(arow + k0);
        float4 bv = *(const float4*)(bbase + (size_t)(k0 + brow) * kH);
        __syncthreads();
        As[lk4 + 0][lrow] = av.x;
        As[lk4 + 1][lrow] = av.y;
        As[lk4 + 2][lrow] = av.z;
        As[lk4 + 3][lrow] = av.w;
        *(float4*)&Bs[brow][bh4] = bv;
        __syncthreads();
#pragma unroll
        for (int kk = 0; kk < 16; ++kk) {
            const float* ap = &As[kk][is << 2];
            const float* bp = &Bs[kk][js << 2];
            float aa[4], bb[4];
#pragma unroll
            for (int c = 0; c < 4; ++c) { aa[c] = ap[c]; bb[c] = bp[c]; }
#pragma unroll
            for (int i = 0; i < 4; ++i)
#pragma unroll
                for (int j = 0; j < 4; ++j)
                    acc[i][j] = fmaf(aa[i], bb[j], acc[i][j]);
        }
    }

#pragma unroll
    for (int i = 0; i < 4; ++i) {
        int row = m0 + (is << 2) + i;
        float4 o = {acc[i][0], acc[i][1], acc[i][2], acc[i][3]};
        *(float4*)(ctx + ((size_t)b * kS + row) * kH + n0 + (js << 2)) = o;
    }
}

extern "C" void kernel_launch(void* const* d_in, const int* in_sizes, int n_in,
                              void* d_out, int out_size, void* d_ws, size_t ws_size,
                              hipStream_t stream)
{
    const float* outputs = (const float*)d_in[0];
    const int*   mask    = (const int*)d_in[1];
    const float* Wa_w    = (const float*)d_in[2];
    const float* Wa_b    = (const float*)d_in[3];
    const float* Ua_w    = (const float*)d_in[4];
    const float* Ua_b    = (const float*)d_in[5];
    const float* Va_w    = (const float*)d_in[6];
    // Va_b and sum(va) cancel in softmax.

    float* attn = (float*)d_out;                          // (B,S,S) 8.39 MB
    float* ctx  = attn + (size_t)kB * kS * kS;            // (B,S,H) 12.58 MB

    // Region reuse over the launch timeline (stream-ordered):
    //   ctx:  [K0..K1] Xhi/Xlo bf16 pair  -> [K2..K3] part1 scores -> [K4] contexts
    //   attn: [K0..K1] W bf16 (hi only)   -> [K2..]   part0 scores / attentions
    unsigned short* Xhi  = (unsigned short*)ctx;
    unsigned short* Xlo  = Xhi + (size_t)kB * kS * kH;
    unsigned short* Wahi = (unsigned short*)attn;
    unsigned short* Uahi = Wahi + (size_t)kH * kH;
    float* part1 = ctx;

    // ws: [wl 128KB][Eqc 9.44MB][EkTc 9.44MB] = 19.0 MB (proven available)
    int* wl = (int*)d_ws;
    float* Eqc  = (float*)((char*)d_ws + 131072);
    float* EkTc = Eqc + (size_t)kB * kJM * kH;

    // K0: RTN bf16 pre-split of X (hi/lo) and RTN bf16 of Wa/Ua
    k0_convert<<<dim3(4224), 256, 0, stream>>>(
        outputs, Wa_w, Ua_w, Xhi, Xlo, Wahi, Uahi);

    // K1 (MFMA, 2-product): Eqc (compacted rows) and EkTc (compacted cols), exp applied
    k1_mfma<<<dim3(kH / 96, (kB * kS) / 128, 2), 256, 0, stream>>>(
        Xhi, Xlo, Wahi, Uahi, Wa_b, Ua_b, mask, Eqc, EkTc);

    // K2a + K2: score partials (h-chunks) into attn (c=0) and part1 (c=1)
    k2a_worklist<<<dim3(1), 256, 0, stream>>>(mask, wl);
    k2_scores<<<dim3(1024), 256, 0, stream>>>(Eqc, EkTc, Va_w, mask, wl, attn, part1);

    // K3: sum partials + softmax + exact-zero masking (writes every element of attn)
    k3_softmax<<<dim3(kB * kS), 256, 0, stream>>>(attn, part1, mask);

    // K4: contexts (writes every element of ctx, overwriting part1 scratch)
    k4_context<<<dim3(kH / 64, kS / 64, kB), 256, 0, stream>>>(attn, outputs, mask, ctx);
}